// Round 1
// baseline (196.910 us; speedup 1.0000x reference)
//
#include <hip/hip_runtime.h>

#define HID 64

__global__ __launch_bounds__(256, 2)
void pihp_kernel(const float* __restrict__ pc,
                 const float* __restrict__ W1, const float* __restrict__ b1,
                 const float* __restrict__ W2, const float* __restrict__ b2,
                 const float* __restrict__ W3, const float* __restrict__ b3,
                 const float* __restrict__ Wmu, const float* __restrict__ bmu,
                 const float* __restrict__ Wlam, const float* __restrict__ blam,
                 float* __restrict__ out, int N)
{
    int idx = blockIdx.x * blockDim.x + threadIdx.x;
    if (idx >= N) return;

    float2 p = reinterpret_cast<const float2*>(pc)[idx];

    float h[HID], g[HID];

    // Layer 1: (2 -> 64), W1 is (2, 64) row-major
    #pragma unroll
    for (int j = 0; j < HID; ++j)
        h[j] = fmaxf(fmaf(p.x, W1[j], fmaf(p.y, W1[HID + j], b1[j])), 0.0f);

    // Layer 2: (64 -> 64), W2 row-major (k, j)
    #pragma unroll
    for (int j = 0; j < HID; ++j) g[j] = b2[j];
    #pragma unroll
    for (int k = 0; k < HID; ++k) {
        float hk = h[k];
        #pragma unroll
        for (int j = 0; j < HID; ++j)
            g[j] = fmaf(hk, W2[k * HID + j], g[j]);
    }
    #pragma unroll
    for (int j = 0; j < HID; ++j) h[j] = fmaxf(g[j], 0.0f);

    // Layer 3: (64 -> 64)
    #pragma unroll
    for (int j = 0; j < HID; ++j) g[j] = b3[j];
    #pragma unroll
    for (int k = 0; k < HID; ++k) {
        float hk = h[k];
        #pragma unroll
        for (int j = 0; j < HID; ++j)
            g[j] = fmaf(hk, W3[k * HID + j], g[j]);
    }
    #pragma unroll
    for (int j = 0; j < HID; ++j) h[j] = fmaxf(g[j], 0.0f);

    // Heads: mu (64 -> 4), lam (64 -> 3)
    float mu[4], lam[3];
    #pragma unroll
    for (int e = 0; e < 4; ++e) mu[e] = bmu[e];
    #pragma unroll
    for (int s = 0; s < 3; ++s) lam[s] = blam[s];
    #pragma unroll
    for (int k = 0; k < HID; ++k) {
        float hk = h[k];
        #pragma unroll
        for (int e = 0; e < 4; ++e) mu[e] = fmaf(hk, Wmu[k * 4 + e], mu[e]);
        #pragma unroll
        for (int s = 0; s < 3; ++s) lam[s] = fmaf(hk, Wlam[k * 3 + s], lam[s]);
    }

    // mu projection: relu, then clip ||G^T mu||_2 <= 1
    // G^T mu = [mu0 - mu1, mu2 - mu3, 0]
    #pragma unroll
    for (int e = 0; e < 4; ++e) mu[e] = fmaxf(mu[e], 0.0f);
    float g0 = mu[0] - mu[1];
    float g1 = mu[2] - mu[3];
    float nrm = sqrtf(g0 * g0 + g1 * g1);
    float scale = (nrm > 1.0f) ? (1.0f / (nrm + 1e-8f)) : 1.0f;

    // lam projection: normalize each column to unit norm
    float ln = sqrtf(lam[0] * lam[0] + lam[1] * lam[1] + lam[2] * lam[2]) + 1e-8f;
    float linv = 1.0f / ln;

    // Output layout: mu is (4, N) then lam is (3, N), concatenated flat
    #pragma unroll
    for (int e = 0; e < 4; ++e)
        out[(size_t)e * N + idx] = mu[e] * scale;
    #pragma unroll
    for (int s = 0; s < 3; ++s)
        out[(size_t)(4 + s) * N + idx] = lam[s] * linv;
}

extern "C" void kernel_launch(void* const* d_in, const int* in_sizes, int n_in,
                              void* d_out, int out_size, void* d_ws, size_t ws_size,
                              hipStream_t stream) {
    const float* pc   = (const float*)d_in[0];
    const float* W1   = (const float*)d_in[1];
    const float* b1   = (const float*)d_in[2];
    const float* W2   = (const float*)d_in[3];
    const float* b2   = (const float*)d_in[4];
    const float* W3   = (const float*)d_in[5];
    const float* b3   = (const float*)d_in[6];
    const float* Wmu  = (const float*)d_in[7];
    const float* bmu  = (const float*)d_in[8];
    const float* Wlam = (const float*)d_in[9];
    const float* blam = (const float*)d_in[10];
    float* out = (float*)d_out;

    int N = in_sizes[0] / 2;  // point_cloud is (N, 2)
    int blocks = (N + 255) / 256;
    pihp_kernel<<<blocks, 256, 0, stream>>>(pc, W1, b1, W2, b2, W3, b3,
                                            Wmu, bmu, Wlam, blam, out, N);
}

// Round 2
// 50.624 us; speedup vs baseline: 3.8897x; 3.8897x over previous
//
#include <hip/hip_runtime.h>

typedef _Float16 h2 __attribute__((ext_vector_type(2)));
typedef _Float16 h8 __attribute__((ext_vector_type(8)));
typedef float    f4 __attribute__((ext_vector_type(4)));

// D = A*B + C formulation per layer:  A = W^T (64 out-feats x 64 in-feats, row-
// permuted), B = H^T (64 in-feats x 16 points).  With the row permutation
//   pi(t, r) = 8*(r>>2) + (r&3) + 4*(t&1) + 32*(t>>1)
// the MFMA C/D layout (lane holds rows 4*(lane/16)+i, col lane%16) is exactly
// the next layer's B-fragment layout (lane holds k = 8*(lane/16)+ii, col
// lane%16) after relu + f16 pack -> zero cross-lane data movement.
__global__ __launch_bounds__(256, 2)
void pihp_mfma(const float* __restrict__ pc,
               const float* __restrict__ W1, const float* __restrict__ b1,
               const float* __restrict__ W2, const float* __restrict__ b2,
               const float* __restrict__ W3, const float* __restrict__ b3,
               const float* __restrict__ Wmu, const float* __restrict__ bmu,
               const float* __restrict__ Wlam, const float* __restrict__ blam,
               float* __restrict__ out, int N)
{
    const int lane = threadIdx.x & 63;
    const int g    = lane >> 4;          // 0..3 : k-group (B) / row-subgroup (C)
    const int m    = lane & 15;          // point-in-slab (B col) / A row
    const int wid  = blockIdx.x * (blockDim.x >> 6) + (threadIdx.x >> 6);
    const int nw   = gridDim.x * (blockDim.x >> 6);

    // ---------------- weight preload (registers, f16 fragments) -------------
    // A-frag: lane holds A[row = m][k = 32c + 8g + ii], row permuted by pi.
    h8 A2[4][2], A3[4][2], Ah[2];
    #pragma unroll
    for (int t = 0; t < 4; ++t) {
        const int j = 8*(m >> 2) + (m & 3) + 4*(t & 1) + 32*(t >> 1); // pi(t,m)
        #pragma unroll
        for (int c = 0; c < 2; ++c) {
            #pragma unroll
            for (int ii = 0; ii < 8; ++ii) {
                const int k = 32*c + 8*g + ii;
                A2[t][c][ii] = (_Float16)W2[k*64 + j];
                A3[t][c][ii] = (_Float16)W3[k*64 + j];
            }
        }
    }
    #pragma unroll
    for (int c = 0; c < 2; ++c) {
        #pragma unroll
        for (int ii = 0; ii < 8; ++ii) {
            const int k = 32*c + 8*g + ii;
            float v = 0.0f;
            if (m < 4)      v = Wmu[k*4 + m];
            else if (m < 7) v = Wlam[k*3 + (m - 4)];
            Ah[c][ii] = (_Float16)v;
        }
    }

    // Bias as MFMA C-init: lane holds D[4g+i][m] -> bias[pi(t, 4g+i)]
    f4 bC2[4], bC3[4], bCh;
    #pragma unroll
    for (int t = 0; t < 4; ++t) {
        #pragma unroll
        for (int i = 0; i < 4; ++i) {
            const int j = 8*g + i + 4*(t & 1) + 32*(t >> 1);   // pi(t, 4g+i)
            bC2[t][i] = b2[j];
            bC3[t][i] = b3[j];
        }
    }
    #pragma unroll
    for (int i = 0; i < 4; ++i) {
        const int rr = 4*g + i;
        bCh[i] = (rr < 4) ? bmu[rr] : (rr < 7 ? blam[rr - 4] : 0.0f);
    }

    // Layer-1 weights packed as half2 pairs in B-frag element order.
    h2 w1x[2][4], w1y[2][4], w1b[2][4];
    #pragma unroll
    for (int c = 0; c < 2; ++c) {
        #pragma unroll
        for (int p = 0; p < 4; ++p) {
            const int k = 32*c + 8*g + 2*p;
            w1x[c][p][0] = (_Float16)W1[k];        w1x[c][p][1] = (_Float16)W1[k+1];
            w1y[c][p][0] = (_Float16)W1[64+k];     w1y[c][p][1] = (_Float16)W1[64+k+1];
            w1b[c][p][0] = (_Float16)b1[k];        w1b[c][p][1] = (_Float16)b1[k+1];
        }
    }

    // ---------------- main loop: 16 points (one slab) per iteration ---------
    const int nslab = (N + 15) >> 4;
    const int per   = (nslab + nw - 1) / nw;
    const int s0 = wid * per;
    const int s1 = (s0 + per < nslab) ? (s0 + per) : nslab;

    for (int s = s0; s < s1; ++s) {
        const int pt = s*16 + m;
        float x = 0.0f, y = 0.0f;
        if (pt < N) {
            const float2 pp = reinterpret_cast<const float2*>(pc)[pt];
            x = pp.x; y = pp.y;
        }
        h2 x2, y2;
        x2[0] = (_Float16)x; x2[1] = (_Float16)x;
        y2[0] = (_Float16)y; y2[1] = (_Float16)y;

        // Layer 1 (2->64) in packed f16, producing the B-fragment directly:
        // B[c][ii] = relu(x*W1[0][k] + y*W1[1][k] + b1[k]), k = 32c+8g+ii
        h8 B[2];
        #pragma unroll
        for (int c = 0; c < 2; ++c) {
            #pragma unroll
            for (int p = 0; p < 4; ++p) {
                h2 v = x2 * w1x[c][p] + y2 * w1y[c][p] + w1b[c][p];
                _Float16 e0 = v[0] > (_Float16)0 ? v[0] : (_Float16)0;
                _Float16 e1 = v[1] > (_Float16)0 ? v[1] : (_Float16)0;
                B[c][2*p]   = e0;
                B[c][2*p+1] = e1;
            }
        }

        // Layer 2: 4 output tiles x 2 K-chunks, bias as C-init
        f4 acc[4];
        #pragma unroll
        for (int t = 0; t < 4; ++t) {
            acc[t] = __builtin_amdgcn_mfma_f32_16x16x32_f16(A2[t][0], B[0], bC2[t], 0, 0, 0);
            acc[t] = __builtin_amdgcn_mfma_f32_16x16x32_f16(A2[t][1], B[1], acc[t], 0, 0, 0);
        }
        // relu + pack: chunk c gets ii0..3 from tile 2c, ii4..7 from tile 2c+1
        #pragma unroll
        for (int c = 0; c < 2; ++c) {
            #pragma unroll
            for (int i = 0; i < 4; ++i) {
                B[c][i]   = (_Float16)fmaxf(acc[2*c][i],   0.0f);
                B[c][4+i] = (_Float16)fmaxf(acc[2*c+1][i], 0.0f);
            }
        }

        // Layer 3
        #pragma unroll
        for (int t = 0; t < 4; ++t) {
            acc[t] = __builtin_amdgcn_mfma_f32_16x16x32_f16(A3[t][0], B[0], bC3[t], 0, 0, 0);
            acc[t] = __builtin_amdgcn_mfma_f32_16x16x32_f16(A3[t][1], B[1], acc[t], 0, 0, 0);
        }
        #pragma unroll
        for (int c = 0; c < 2; ++c) {
            #pragma unroll
            for (int i = 0; i < 4; ++i) {
                B[c][i]   = (_Float16)fmaxf(acc[2*c][i],   0.0f);
                B[c][4+i] = (_Float16)fmaxf(acc[2*c+1][i], 0.0f);
            }
        }

        // Heads (64 -> 7, padded to one 16-row tile), no permutation:
        // lane g=0 ends with mu0..3 in hacc[0..3]; lane g=1 with lam0..2.
        f4 hacc;
        hacc = __builtin_amdgcn_mfma_f32_16x16x32_f16(Ah[0], B[0], bCh, 0, 0, 0);
        hacc = __builtin_amdgcn_mfma_f32_16x16x32_f16(Ah[1], B[1], hacc, 0, 0, 0);

        if (pt < N) {
            if (g == 0) {
                const float mu0 = fmaxf(hacc[0], 0.0f), mu1 = fmaxf(hacc[1], 0.0f);
                const float mu2 = fmaxf(hacc[2], 0.0f), mu3 = fmaxf(hacc[3], 0.0f);
                const float g0 = mu0 - mu1, g1 = mu2 - mu3;
                const float nrm = sqrtf(g0*g0 + g1*g1);
                const float sc  = (nrm > 1.0f) ? (1.0f / (nrm + 1e-8f)) : 1.0f;
                out[(size_t)0*N + pt] = mu0 * sc;
                out[(size_t)1*N + pt] = mu1 * sc;
                out[(size_t)2*N + pt] = mu2 * sc;
                out[(size_t)3*N + pt] = mu3 * sc;
            } else if (g == 1) {
                const float l0 = hacc[0], l1 = hacc[1], l2 = hacc[2];
                const float inv = 1.0f / (sqrtf(l0*l0 + l1*l1 + l2*l2) + 1e-8f);
                out[(size_t)4*N + pt] = l0 * inv;
                out[(size_t)5*N + pt] = l1 * inv;
                out[(size_t)6*N + pt] = l2 * inv;
            }
        }
    }
}

extern "C" void kernel_launch(void* const* d_in, const int* in_sizes, int n_in,
                              void* d_out, int out_size, void* d_ws, size_t ws_size,
                              hipStream_t stream) {
    const float* pc   = (const float*)d_in[0];
    const float* W1   = (const float*)d_in[1];
    const float* b1   = (const float*)d_in[2];
    const float* W2   = (const float*)d_in[3];
    const float* b2   = (const float*)d_in[4];
    const float* W3   = (const float*)d_in[5];
    const float* b3   = (const float*)d_in[6];
    const float* Wmu  = (const float*)d_in[7];
    const float* bmu  = (const float*)d_in[8];
    const float* Wlam = (const float*)d_in[9];
    const float* blam = (const float*)d_in[10];
    float* out = (float*)d_out;

    const int N = in_sizes[0] / 2;   // point_cloud is (N, 2)
    // 512 blocks x 4 waves = 2048 waves ~= one full-occupancy pass at 2 waves/SIMD
    pihp_mfma<<<512, 256, 0, stream>>>(pc, W1, b1, W2, b2, W3, b3,
                                       Wmu, bmu, Wlam, blam, out, N);
}

// Round 3
// 46.208 us; speedup vs baseline: 4.2614x; 1.0956x over previous
//
#include <hip/hip_runtime.h>

typedef _Float16 h2 __attribute__((ext_vector_type(2)));
typedef _Float16 h8 __attribute__((ext_vector_type(8)));
typedef float    f4 __attribute__((ext_vector_type(4)));

// D = A*B + C per layer:  A = W^T (row-permuted), B = H^T (64 feats x 16 pts).
// Row permutation pi(t, r) = 8*(r>>2) + (r&3) + 4*(t&1) + 32*(t>>1) makes the
// MFMA C/D layout equal the next layer's B-fragment layout after relu+pack.
// Round 3: two slabs (32 points) in flight per wave, interleaved MFMAs,
// explicit point prefetch -> 4 independent chains per SIMD at 2 waves/SIMD.
__global__ __launch_bounds__(256, 2)
void pihp_mfma(const float* __restrict__ pc,
               const float* __restrict__ W1, const float* __restrict__ b1,
               const float* __restrict__ W2, const float* __restrict__ b2,
               const float* __restrict__ W3, const float* __restrict__ b3,
               const float* __restrict__ Wmu, const float* __restrict__ bmu,
               const float* __restrict__ Wlam, const float* __restrict__ blam,
               float* __restrict__ out, int N)
{
    const int lane = threadIdx.x & 63;
    const int g    = lane >> 4;          // k-group (B) / row-subgroup (C/D)
    const int m    = lane & 15;          // point-in-slab (B col) / A row
    const int wid  = blockIdx.x * (blockDim.x >> 6) + (threadIdx.x >> 6);
    const int nw   = gridDim.x * (blockDim.x >> 6);

    const int nslab = (N + 15) >> 4;
    int per = (nslab + nw - 1) / nw;
    per = (per + 1) & ~1;                              // even
    const int s0 = wid * per;
    if (s0 >= nslab) return;
    const int s1 = (s0 + per < nslab) ? (s0 + per) : nslab;

    // ---------------- weight preload (registers, f16 fragments) -------------
    h8 A2[4][2], A3[4][2], Ah[2];
    #pragma unroll
    for (int t = 0; t < 4; ++t) {
        const int j = 8*(m >> 2) + (m & 3) + 4*(t & 1) + 32*(t >> 1); // pi(t,m)
        #pragma unroll
        for (int c = 0; c < 2; ++c) {
            #pragma unroll
            for (int ii = 0; ii < 8; ++ii) {
                const int k = 32*c + 8*g + ii;
                A2[t][c][ii] = (_Float16)W2[k*64 + j];
                A3[t][c][ii] = (_Float16)W3[k*64 + j];
            }
        }
    }
    #pragma unroll
    for (int c = 0; c < 2; ++c) {
        #pragma unroll
        for (int ii = 0; ii < 8; ++ii) {
            const int k = 32*c + 8*g + ii;
            float v = 0.0f;
            if (m < 4)      v = Wmu[k*4 + m];
            else if (m < 7) v = Wlam[k*3 + (m - 4)];
            Ah[c][ii] = (_Float16)v;
        }
    }

    f4 bC2[4], bC3[4], bCh;
    #pragma unroll
    for (int t = 0; t < 4; ++t) {
        #pragma unroll
        for (int i = 0; i < 4; ++i) {
            const int j = 8*g + i + 4*(t & 1) + 32*(t >> 1);   // pi(t, 4g+i)
            bC2[t][i] = b2[j];
            bC3[t][i] = b3[j];
        }
    }
    #pragma unroll
    for (int i = 0; i < 4; ++i) {
        const int rr = 4*g + i;
        bCh[i] = (rr < 4) ? bmu[rr] : (rr < 7 ? blam[rr - 4] : 0.0f);
    }

    h2 w1x[2][4], w1y[2][4], w1b[2][4];
    #pragma unroll
    for (int c = 0; c < 2; ++c) {
        #pragma unroll
        for (int p = 0; p < 4; ++p) {
            const int k = 32*c + 8*g + 2*p;
            w1x[c][p][0] = (_Float16)W1[k];        w1x[c][p][1] = (_Float16)W1[k+1];
            w1y[c][p][0] = (_Float16)W1[64+k];     w1y[c][p][1] = (_Float16)W1[64+k+1];
            w1b[c][p][0] = (_Float16)b1[k];        w1b[c][p][1] = (_Float16)b1[k+1];
        }
    }

    const float2* __restrict__ pcv = reinterpret_cast<const float2*>(pc);
    const int Nm1 = N - 1;
    auto clampload = [&](int ss) -> float2 {
        int pt = ss*16 + m;
        pt = pt < Nm1 ? pt : Nm1;           // unconditional, memory-safe
        return pcv[pt];
    };

    float2 Pc0 = clampload(s0);
    float2 Pc1 = clampload(s0 + 1);

    for (int ss = s0; ss < s1; ss += 2) {
        // prefetch next pair (values only used next iteration; clamped safe)
        float2 Pn0 = clampload(ss + 2);
        float2 Pn1 = clampload(ss + 3);

        // Layer 1 (2->64) packed f16, produces B-fragments directly
        h8 B0[2], B1[2];
        {
            h2 x0, y0, x1, y1;
            x0[0] = (_Float16)Pc0.x; x0[1] = x0[0];
            y0[0] = (_Float16)Pc0.y; y0[1] = y0[0];
            x1[0] = (_Float16)Pc1.x; x1[1] = x1[0];
            y1[0] = (_Float16)Pc1.y; y1[1] = y1[0];
            #pragma unroll
            for (int c = 0; c < 2; ++c) {
                #pragma unroll
                for (int p = 0; p < 4; ++p) {
                    h2 v0 = x0 * w1x[c][p] + y0 * w1y[c][p] + w1b[c][p];
                    h2 v1 = x1 * w1x[c][p] + y1 * w1y[c][p] + w1b[c][p];
                    const _Float16 z = (_Float16)0;
                    B0[c][2*p]   = v0[0] > z ? v0[0] : z;
                    B0[c][2*p+1] = v0[1] > z ? v0[1] : z;
                    B1[c][2*p]   = v1[0] > z ? v1[0] : z;
                    B1[c][2*p+1] = v1[1] > z ? v1[1] : z;
                }
            }
        }

        f4 a0[4], a1[4];

        // Layer 2: interleaved across the two slabs
        #pragma unroll
        for (int t = 0; t < 4; ++t) {
            a0[t] = __builtin_amdgcn_mfma_f32_16x16x32_f16(A2[t][0], B0[0], bC2[t], 0, 0, 0);
            a1[t] = __builtin_amdgcn_mfma_f32_16x16x32_f16(A2[t][0], B1[0], bC2[t], 0, 0, 0);
        }
        #pragma unroll
        for (int t = 0; t < 4; ++t) {
            a0[t] = __builtin_amdgcn_mfma_f32_16x16x32_f16(A2[t][1], B0[1], a0[t], 0, 0, 0);
            a1[t] = __builtin_amdgcn_mfma_f32_16x16x32_f16(A2[t][1], B1[1], a1[t], 0, 0, 0);
        }
        #pragma unroll
        for (int c = 0; c < 2; ++c) {
            #pragma unroll
            for (int i = 0; i < 4; ++i) {
                B0[c][i]   = (_Float16)fmaxf(a0[2*c][i],   0.0f);
                B0[c][4+i] = (_Float16)fmaxf(a0[2*c+1][i], 0.0f);
                B1[c][i]   = (_Float16)fmaxf(a1[2*c][i],   0.0f);
                B1[c][4+i] = (_Float16)fmaxf(a1[2*c+1][i], 0.0f);
            }
        }

        // Layer 3
        #pragma unroll
        for (int t = 0; t < 4; ++t) {
            a0[t] = __builtin_amdgcn_mfma_f32_16x16x32_f16(A3[t][0], B0[0], bC3[t], 0, 0, 0);
            a1[t] = __builtin_amdgcn_mfma_f32_16x16x32_f16(A3[t][0], B1[0], bC3[t], 0, 0, 0);
        }
        #pragma unroll
        for (int t = 0; t < 4; ++t) {
            a0[t] = __builtin_amdgcn_mfma_f32_16x16x32_f16(A3[t][1], B0[1], a0[t], 0, 0, 0);
            a1[t] = __builtin_amdgcn_mfma_f32_16x16x32_f16(A3[t][1], B1[1], a1[t], 0, 0, 0);
        }
        #pragma unroll
        for (int c = 0; c < 2; ++c) {
            #pragma unroll
            for (int i = 0; i < 4; ++i) {
                B0[c][i]   = (_Float16)fmaxf(a0[2*c][i],   0.0f);
                B0[c][4+i] = (_Float16)fmaxf(a0[2*c+1][i], 0.0f);
                B1[c][i]   = (_Float16)fmaxf(a1[2*c][i],   0.0f);
                B1[c][4+i] = (_Float16)fmaxf(a1[2*c+1][i], 0.0f);
            }
        }

        // Heads (64 -> 7 padded): lane g=0 gets mu0..3, g=1 gets lam0..2
        f4 h0, h1;
        h0 = __builtin_amdgcn_mfma_f32_16x16x32_f16(Ah[0], B0[0], bCh, 0, 0, 0);
        h1 = __builtin_amdgcn_mfma_f32_16x16x32_f16(Ah[0], B1[0], bCh, 0, 0, 0);
        h0 = __builtin_amdgcn_mfma_f32_16x16x32_f16(Ah[1], B0[1], h0, 0, 0, 0);
        h1 = __builtin_amdgcn_mfma_f32_16x16x32_f16(Ah[1], B1[1], h1, 0, 0, 0);

        // Epilogue + stores, slab u=0 then u=1
        #pragma unroll
        for (int u = 0; u < 2; ++u) {
            const f4 hv = (u == 0) ? h0 : h1;
            const int pt = (ss + u)*16 + m;
            if (pt < N) {
                if (g == 0) {
                    const float mu0 = fmaxf(hv[0], 0.0f), mu1 = fmaxf(hv[1], 0.0f);
                    const float mu2 = fmaxf(hv[2], 0.0f), mu3 = fmaxf(hv[3], 0.0f);
                    const float g0 = mu0 - mu1, g1 = mu2 - mu3;
                    const float nrm = sqrtf(g0*g0 + g1*g1);
                    const float sc  = (nrm > 1.0f) ? (1.0f / (nrm + 1e-8f)) : 1.0f;
                    out[(size_t)0*N + pt] = mu0 * sc;
                    out[(size_t)1*N + pt] = mu1 * sc;
                    out[(size_t)2*N + pt] = mu2 * sc;
                    out[(size_t)3*N + pt] = mu3 * sc;
                } else if (g == 1) {
                    const float l0 = hv[0], l1 = hv[1], l2 = hv[2];
                    const float inv = 1.0f / (sqrtf(l0*l0 + l1*l1 + l2*l2) + 1e-8f);
                    out[(size_t)4*N + pt] = l0 * inv;
                    out[(size_t)5*N + pt] = l1 * inv;
                    out[(size_t)6*N + pt] = l2 * inv;
                }
            }
        }

        Pc0 = Pn0;
        Pc1 = Pn1;
    }
}

extern "C" void kernel_launch(void* const* d_in, const int* in_sizes, int n_in,
                              void* d_out, int out_size, void* d_ws, size_t ws_size,
                              hipStream_t stream) {
    const float* pc   = (const float*)d_in[0];
    const float* W1   = (const float*)d_in[1];
    const float* b1   = (const float*)d_in[2];
    const float* W2   = (const float*)d_in[3];
    const float* b2   = (const float*)d_in[4];
    const float* W3   = (const float*)d_in[5];
    const float* b3   = (const float*)d_in[6];
    const float* Wmu  = (const float*)d_in[7];
    const float* bmu  = (const float*)d_in[8];
    const float* Wlam = (const float*)d_in[9];
    const float* blam = (const float*)d_in[10];
    float* out = (float*)d_out;

    const int N = in_sizes[0] / 2;   // point_cloud is (N, 2)
    pihp_mfma<<<512, 256, 0, stream>>>(pc, W1, b1, W2, b2, W3, b3,
                                       Wmu, bmu, Wlam, blam, out, N);
}